// Round 2
// baseline (229.407 us; speedup 1.0000x reference)
//
#include <hip/hip_runtime.h>
#include <hip/hip_bf16.h>

#define NN 4096
#define CAP 128   // max nnz per row tracked (binomial mean 41, sd 6.4)
#define KS 8      // k-splits for P-GEMM

typedef __attribute__((ext_vector_type(8))) short bf16x8;
typedef __attribute__((ext_vector_type(4))) float f32x4;

__device__ __forceinline__ float lrelu(float v) { return v >= 0.f ? v : 0.2f * v; }

// fp32 -> bf16 bits, round-to-nearest-even (inputs are finite)
__device__ __forceinline__ ushort f2bu(float f) {
    unsigned u = __float_as_uint(f);
    return (ushort)((u + 0x7FFFu + ((u >> 16) & 1u)) >> 16);
}

// ---------------------------------------------------------------------------
// K1: xwA1=x@W1[0], xwB1=x@W1[1], xwA2=x@W2[0], xwB2=x@W2[1], v0=x@W0,
//     a/b attention vectors, Bt = (x@W0)^T as bf16 for the P-GEMM.
// ---------------------------------------------------------------------------
__global__ __launch_bounds__(256) void k_prep(
    const float* __restrict__ x,
    const float* __restrict__ W1, const float* __restrict__ W2,
    const float* __restrict__ W0,
    const float* __restrict__ att1, const float* __restrict__ att2,
    float* __restrict__ xwA1, float* __restrict__ xwB1,
    float* __restrict__ xwA2, float* __restrict__ xwB2,
    float* __restrict__ a1, float* __restrict__ b1,
    float* __restrict__ a2, float* __restrict__ b2,
    __hip_bfloat16* __restrict__ Bt)
{
    __shared__ float wl[5120];   // W1(2048) W2(2048) W0(1024)
    __shared__ float xs[256];    // 8 rows x 32
    const int t = threadIdx.x;
    for (int i = t; i < 2048; i += 256) { wl[i] = W1[i]; wl[2048 + i] = W2[i]; }
    for (int i = t; i < 1024; i += 256) wl[4096 + i] = W0[i];
    const int rowBase = blockIdx.x * 8;
    xs[t] = x[rowBase * 32 + t];
    __syncthreads();

    const int o = t & 31, r = t >> 5;
    const int row = rowBase + r;
    const float* xr = &xs[r * 32];
    float vA1 = 0.f, vB1 = 0.f, vA2 = 0.f, vB2 = 0.f, v0 = 0.f;
#pragma unroll
    for (int f = 0; f < 32; ++f) {
        const float xv = xr[f];
        vA1 += xv * wl[f * 32 + o];
        vB1 += xv * wl[1024 + f * 32 + o];
        vA2 += xv * wl[2048 + f * 32 + o];
        vB2 += xv * wl[3072 + f * 32 + o];
        v0  += xv * wl[4096 + f * 32 + o];
    }
    xwA1[row * 32 + o] = vA1;
    xwB1[row * 32 + o] = vB1;
    xwA2[row * 32 + o] = vA2;
    xwB2[row * 32 + o] = vB2;
    ((ushort*)Bt)[(size_t)o * NN + row] = f2bu(v0);

    float pa1 = vA1 * att1[o]      + vB1 * att1[32 + o];
    float pb1 = vA1 * att1[64 + o] + vB1 * att1[96 + o];
    float pa2 = vA2 * att2[o]      + vB2 * att2[32 + o];
    float pb2 = vA2 * att2[64 + o] + vB2 * att2[96 + o];
#pragma unroll
    for (int m = 1; m <= 16; m <<= 1) {
        pa1 += __shfl_xor(pa1, m); pb1 += __shfl_xor(pb1, m);
        pa2 += __shfl_xor(pa2, m); pb2 += __shfl_xor(pb2, m);
    }
    if (o == 0) { a1[row] = pa1; b1[row] = pb1; a2[row] = pa2; b2[row] = pb2; }
}

// ---------------------------------------------------------------------------
// K2 (k_scan4): WAVE-AUTONOMOUS rewrite. One wave per (row, branch); zero
// __syncthreads. Stream 16 KB row in 4 register chunks, wave-local ballot
// compaction into a wave-private LDS list, wave-shuffle softmax, write
// normalized weights to csrv, fused y-gather u = xwA + L@xwB.
// Grid (1024,2) x 256 = 8 blocks/CU exactly, 32 independent waves/CU.
// ---------------------------------------------------------------------------
__global__ __launch_bounds__(256) void k_scan4(
    const float* __restrict__ Ld, const float* __restrict__ Lu,
    const float* __restrict__ xwB1, const float* __restrict__ xwB2,
    const float* __restrict__ xwA1, const float* __restrict__ xwA2,
    const float* __restrict__ a1, const float* __restrict__ b1,
    const float* __restrict__ a2, const float* __restrict__ b2,
    int2* __restrict__ csrv, int* __restrict__ cntArr,
    float* __restrict__ u1, float* __restrict__ u2)
{
    const int t = threadIdx.x;
    const int lane = t & 63, w = t >> 6;
    const int row = blockIdx.x * 4 + w;
    const int br  = blockIdx.y;
    const float* L   = br ? Lu : Ld;
    const float* xwB = br ? xwB2 : xwB1;
    const float* xwA = br ? xwA2 : xwA1;
    const float* aA  = br ? a2 : a1;
    const float* bA  = br ? b2 : b1;
    int2* csrB = csrv + ((size_t)br * NN + row) * CAP;
    float* u   = br ? u2 : u1;

    __shared__ int2 slist_all[4][CAP];   // wave-private lists: (idx, raw L bits)
    int2* slist = slist_all[w];

    const float4* L4 = (const float4*)(L + (size_t)row * NN);
    const unsigned long long lt = (1ull << lane) - 1ull;
    int base = 0;

    // stream the row: 4 chunks of 4 float4 per lane; wave-local compaction
#pragma unroll 1
    for (int c = 0; c < 4; ++c) {
        float4 v[4];
#pragma unroll
        for (int j = 0; j < 4; ++j) v[j] = L4[c * 256 + j * 64 + lane];
#pragma unroll
        for (int j = 0; j < 4; ++j) {
            const float vx = v[j].x, vy = v[j].y, vz = v[j].z, vw = v[j].w;
            const unsigned long long m0 = __ballot(vx != 0.f);
            const unsigned long long m1 = __ballot(vy != 0.f);
            const unsigned long long m2 = __ballot(vz != 0.f);
            const unsigned long long m3 = __ballot(vw != 0.f);
            const int p0 = __popcll(m0), p1 = __popcll(m1), p2 = __popcll(m2);
            const int c0 = (c * 256 + j * 64 + lane) * 4;
            int s;
            s = base + __popcll(m0 & lt);
            if (vx != 0.f && s < CAP) { int2 e; e.x = c0;     e.y = __float_as_int(vx); slist[s] = e; }
            s = base + p0 + __popcll(m1 & lt);
            if (vy != 0.f && s < CAP) { int2 e; e.x = c0 + 1; e.y = __float_as_int(vy); slist[s] = e; }
            s = base + p0 + p1 + __popcll(m2 & lt);
            if (vz != 0.f && s < CAP) { int2 e; e.x = c0 + 2; e.y = __float_as_int(vz); slist[s] = e; }
            s = base + p0 + p1 + p2 + __popcll(m3 & lt);
            if (vw != 0.f && s < CAP) { int2 e; e.x = c0 + 3; e.y = __float_as_int(vw); slist[s] = e; }
            base += p0 + p1 + p2 + __popcll(m3);
        }
    }

    const int cnt  = min(base, CAP);
    const int cpad = min((cnt + 15) & ~15, CAP);   // k_accum expects 16-padding
    // sentinel padding (at most 15 slots): idx 0, value 0
    const int ps = cnt + lane;
    if (ps < cpad) { int2 z; z.x = 0; z.y = 0; slist[ps] = z; }

    // same-wave LDS RAW fence (wave executes in lockstep; this wave's ds ops
    // cover all 64 lanes). Prevent any compiler reordering across it.
    asm volatile("s_waitcnt lgkmcnt(0)" ::: "memory");
    __builtin_amdgcn_sched_barrier(0);

    // --- wave-shuffle softmax over the list: lane owns slots lane, lane+64 ---
    const float ai = aA[row];
    int iA = 0, iB = 0;
    float eA = -1e30f, eB = -1e30f;
    if (lane < cnt)      { iA = slist[lane].x;      eA = lrelu(ai + bA[iA]); }
    if (64 + lane < cnt) { iB = slist[64 + lane].x; eB = lrelu(ai + bA[iB]); }
    float mx = fmaxf(eA, eB);
#pragma unroll
    for (int mm = 1; mm <= 32; mm <<= 1) mx = fmaxf(mx, __shfl_xor(mx, mm));
    const float w0 = (lane < cnt)      ? __expf(eA - mx) : 0.f;
    const float w1 = (64 + lane < cnt) ? __expf(eB - mx) : 0.f;
    float ss = w0 + w1;
#pragma unroll
    for (int mm = 1; mm <= 32; mm <<= 1) ss += __shfl_xor(ss, mm);
    const float inv = (cnt > 0) ? 1.f / ss : 0.f;
    if (lane < cpad)      { int2 eo; eo.x = iA; eo.y = __float_as_int(w0 * inv); csrB[lane] = eo; }
    if (64 + lane < cpad) { int2 eo; eo.x = iB; eo.y = __float_as_int(w1 * inv); csrB[64 + lane] = eo; }
    if (lane == 0) cntArr[br * NN + row] = cnt;

    // --- fused y-gather (raw L values in slist): 2 groups of 32 lanes ---
    const int o = lane & 31, g = lane >> 5;
    float acc = 0.f;
    for (int s0 = 0; s0 < cpad; s0 += 8) {
        float vv[4], uu[4];
#pragma unroll
        for (int q = 0; q < 4; ++q) {
            const int2 e = slist[s0 + 2 * q + g];
            vv[q] = __int_as_float(e.y);
            uu[q] = xwB[(size_t)e.x * 32 + o];
        }
#pragma unroll
        for (int q = 0; q < 4; ++q) acc += vv[q] * uu[q];
    }
    acc += __shfl_xor(acc, 32);
    if (lane < 32) u[(size_t)row * 32 + o] = acc + xwA[(size_t)row * 32 + o];
}

// ---------------------------------------------------------------------------
// K3 (k_accum): wave per row. Pure weighted gather of U for both branches
// (weights pre-normalized in csrv), fold in KS partials, write d_out.
// ---------------------------------------------------------------------------
__global__ __launch_bounds__(256) void k_accum(
    const int2* __restrict__ csrv, const int* __restrict__ cntArr,
    const float* __restrict__ u1, const float* __restrict__ u2,
    const float* __restrict__ partial, float* __restrict__ outp)
{
    __shared__ int2 sle[4][2 * CAP];
    const int w = threadIdx.x >> 6, lane = threadIdx.x & 63;
    const int row = blockIdx.x * 4 + w;
    const int o = lane & 31, g = lane >> 5;
    int2* se = sle[w];
    float total = 0.f;

    int cp[2];
#pragma unroll
    for (int br = 0; br < 2; ++br) {
        const int cnt = cntArr[br * NN + row];
        cp[br] = min((cnt + 15) & ~15, CAP);
        const int2* ci = csrv + ((size_t)br * NN + row) * CAP;
        if (lane < cp[br])      se[br * CAP + lane]      = ci[lane];
        if (lane + 64 < cp[br]) se[br * CAP + lane + 64] = ci[lane + 64];
    }
    // wave-private LDS segment; same-wave ordering

#pragma unroll
    for (int br = 0; br < 2; ++br) {
        const float* U = br ? u2 : u1;
        float acc = 0.f;
        const int nb = cp[br] >> 3;
        for (int j = 0; j < nb; ++j) {
            float wv[4], uv[4];
#pragma unroll
            for (int q = 0; q < 4; ++q) {
                const int2 e = se[br * CAP + 8 * j + 2 * q + g];
                wv[q] = __int_as_float(e.y);
                uv[q] = U[(size_t)e.x * 32 + o];
            }
#pragma unroll
            for (int q = 0; q < 4; ++q) acc += wv[q] * uv[q];
        }
        acc += __shfl_xor(acc, 32);
        total += acc;
    }

    if (lane < 32) {
#pragma unroll
        for (int p = 0; p < KS; ++p)
            total += partial[(size_t)p * NN * 32 + (size_t)row * 32 + o];
        outp[(size_t)row * 32 + o] = total;
    }
}

// ---------------------------------------------------------------------------
// K4 (MFMA): partial[ks] = P[:, krange] @ B[krange, :]
// Block = 64 rows x 32 cols x 512 k; 4 chunks of 128 k, double-buffered LDS.
// ---------------------------------------------------------------------------
__global__ __launch_bounds__(256) void k_pgemm(
    const float* __restrict__ P, const ushort* __restrict__ Bt,
    float* __restrict__ partial)
{
    __shared__ ushort sA[2][16 * 64 * 8];
    __shared__ ushort sB[2][8 * 64 * 8];
    const int t = threadIdx.x;
    const int row0 = blockIdx.x * 64;
    const int ks = blockIdx.y;
    const float4*  P4  = (const float4*)P;
    const ushort4* Bt4 = (const ushort4*)Bt;

    const int lane = t & 63, w = t >> 6;

    f32x4 acc0 = {0.f, 0.f, 0.f, 0.f};
    f32x4 acc1 = {0.f, 0.f, 0.f, 0.f};

    auto stageA = [&](int c, int buf) {
        const int kc4 = (ks * 512 + c * 128) >> 2;
#pragma unroll
        for (int j = 0; j < 8; ++j) {
            const int i = t + 256 * j;
            const int row = i >> 5, q = i & 31;
            const float4 v = P4[(size_t)(row0 + row) * 1024 + kc4 + q];
            ushort4 u;
            u.x = f2bu(v.x); u.y = f2bu(v.y); u.z = f2bu(v.z); u.w = f2bu(v.w);
            const int wi = row >> 4, m = row & 15;
            const int kk = q >> 3, quad = (q >> 1) & 3, jj = q & 1;
            *(ushort4*)&sA[buf][(((wi * 4 + kk) * 64) + quad * 16 + m) * 8 + jj * 4] = u;
        }
    };
    auto stageB = [&](int c, int buf) {
        const int kc4 = (ks * 512 + c * 128) >> 2;
#pragma unroll
        for (int j = 0; j < 4; ++j) {
            const int i = t + 256 * j;
            const int o = i >> 5, q = i & 31;
            const ushort4 u = Bt4[(size_t)o * 1024 + kc4 + q];
            const int nt = o >> 4, n = o & 15;
            const int kk = q >> 3, quad = (q >> 1) & 3, jj = q & 1;
            *(ushort4*)&sB[buf][(((kk * 2 + nt) * 64) + quad * 16 + n) * 8 + jj * 4] = u;
        }
    };
    auto compute = [&](int buf) {
        const ushort* pa = &sA[buf][(w * 4) * 64 * 8 + lane * 8];
        const ushort* pb = &sB[buf][lane * 8];
#pragma unroll
        for (int kk = 0; kk < 4; ++kk) {
            const bf16x8 a  = *(const bf16x8*)(pa + kk * 512);
            const bf16x8 b0 = *(const bf16x8*)(pb + kk * 1024);
            const bf16x8 b1 = *(const bf16x8*)(pb + kk * 1024 + 512);
            acc0 = __builtin_amdgcn_mfma_f32_16x16x32_bf16(a, b0, acc0, 0, 0, 0);
            acc1 = __builtin_amdgcn_mfma_f32_16x16x32_bf16(a, b1, acc1, 0, 0, 0);
        }
    };

    stageA(0, 0); stageB(0, 0);
    __syncthreads();
    for (int c = 0; c < 4; ++c) {
        if (c < 3) { stageA(c + 1, (c + 1) & 1); stageB(c + 1, (c + 1) & 1); }
        compute(c & 1);
        __syncthreads();
    }

    const int m = lane & 15, quad = lane >> 4;
    float* out = partial + ((size_t)ks * NN + row0 + w * 16 + quad * 4) * 32;
#pragma unroll
    for (int r = 0; r < 4; ++r) {
        out[r * 32 + m]      = acc0[r];
        out[r * 32 + 16 + m] = acc1[r];
    }
}

extern "C" void kernel_launch(void* const* d_in, const int* in_sizes, int n_in,
                              void* d_out, int out_size, void* d_ws, size_t ws_size,
                              hipStream_t stream) {
    (void)in_sizes; (void)n_in; (void)out_size; (void)ws_size;
    const float* x    = (const float*)d_in[0];
    const float* Ld   = (const float*)d_in[1];
    const float* Lu   = (const float*)d_in[2];
    const float* P    = (const float*)d_in[3];
    const float* W1   = (const float*)d_in[4];
    const float* W2   = (const float*)d_in[5];
    const float* W0   = (const float*)d_in[6];
    const float* att1 = (const float*)d_in[7];
    const float* att2 = (const float*)d_in[8];

    float* ws = (float*)d_ws;
    float* xwA1 = ws;                 // 131072 each
    float* xwB1 = ws + 131072;
    float* xwA2 = ws + 262144;
    float* xwB2 = ws + 393216;
    float* u1   = ws + 524288;        // xwA + L@xwB (fused)
    float* u2   = ws + 655360;
    float* a1   = ws + 786432;        // 4096 each
    float* b1   = ws + 790528;
    float* a2   = ws + 794624;
    float* b2   = ws + 798720;
    float* partial = ws + 802816;           // KS*131072 floats = 4 MB
    __hip_bfloat16* Bt = (__hip_bfloat16*)(ws + 1851392);   // 131072 bf16
    int2* csrv = (int2*)(ws + 1916928);     // 2*4096*128 int2 = 8 MB
    int*  cnt  = (int*)(ws + 4014080);      // 8192 ints

    k_prep<<<512, 256, 0, stream>>>(x, W1, W2, W0, att1, att2,
                                    xwA1, xwB1, xwA2, xwB2, a1, b1, a2, b2, Bt);
    k_scan4<<<dim3(NN / 4, 2), 256, 0, stream>>>(Ld, Lu, xwB1, xwB2, xwA1, xwA2,
                                                 a1, b1, a2, b2, csrv, cnt, u1, u2);
    k_pgemm<<<dim3(64, KS), 256, 0, stream>>>(P, (const ushort*)Bt, partial);
    k_accum<<<NN / 4, 256, 0, stream>>>(csrv, cnt, u1, u2, partial,
                                        (float*)d_out);
}